// Round 4
// baseline (65.979 us; speedup 1.0000x reference)
//
#include <hip/hip_runtime.h>

// One wavefront = one 9-qubit patch circuit. Two-kernel structure:
// feats -> d_ws, then a tiny FC kernel (R8 atomics regression: cross-XCD
// fan-in costs more than a second launch; R7: never grid-fence).
//
// R11 (this round): entire hot path rewritten on float2 VECTOR expressions
// (HIP float2 = ext_vector_type(2)) so clang emits <2 x float> IR and ISel
// selects packed dual-f32 VOP3P (v_pk_fma_f32 / v_pk_mul_f32):
//   cmul = 2 packed instr (was 4 scalar); g2 apply = 10 (was 16);
//   CRX/RY pair = 4 (was 8); measurement partials = 3 pk_fma per reg-pair.
// State held as float2 amp[8] (re,im adjacent = natural packed pairs).
// feats store: one coalesced 3-lane store (lanes 0..2) instead of 3 dwords
// from lane 0.
//
// R10: weight-only gate chains PRE-COMPOSED into 2x2 complex matrices by
// wave 0, shared block-wide via one __syncthreads (12 factor mats = pool1
// RX x conv2 RY x conv2 RZ; 3 post mats M0_0/M0_1/M6_1 via q3 block-diag
// + RZ0(w38) commuting past CX(0,6)).
// R9 drops: RZ(q3,w31), RZ(q6,w39) eliminated by commutation; final
// RY(q0,w41) folded into the measurement basis.
//
// Qubit -> bit remap:
//   qubit 0 -> reg bit 0  qubit 3 -> reg bit 1  qubit 6 -> reg bit 2
//   qubit 1 -> lane bit 0  qubit 2 -> lane bit 1  qubit 4 -> lane bit 2
//   qubit 5 -> lane bit 3  qubit 7 -> lane bit 4  qubit 8 -> lane bit 5
//
// Pipeline (pieces correctness-proven R6-R10):
//   enc RY + conv1 RY -> per-qubit (c,s); conv1 RZ folds into tau_q(b)
//   ring CNOT eliminated analytically -> per-lane product state
//   pool1+conv2 -> one 2x2 matrix per factor
//   CX(0,3),CX(3,6),CX(6,0) folded into expansion indexing:
//     v(b0,b1,b2) = p0(b0^b2) * p1(b0^b1^b2) * p2(b1^b2)
//   post gates via per-q3-half composed matrices; measure qubit0.

__device__ __forceinline__ float shx(float v, int m) { return __shfl_xor(v, m, 64); }

__device__ __forceinline__ float2 f2b(float v) { return make_float2(v, v); }

// complex multiply as packed ops: (a.x)*b + (-a.y, a.y)*(b.y, b.x)
__device__ __forceinline__ float2 cmul(float2 a, float2 b) {
  return f2b(a.x) * b + make_float2(-a.y, a.y) * make_float2(b.y, b.x);
}

// general 2x2 complex matrix on a 2-vector; rows packed as
// float4 = (m00r, m00i, m01r, m01i) / (m10r, m10i, m11r, m11i)
__device__ __forceinline__
void g2_f(float2& A, float2& B, float4 R0, float4 R1) {
  const float2 nA = cmul(make_float2(R0.x, R0.y), A) + cmul(make_float2(R0.z, R0.w), B);
  const float2 nB = cmul(make_float2(R1.x, R1.y), A) + cmul(make_float2(R1.z, R1.w), B);
  A = nA; B = nB;
}

template <int RA, int RB> __device__ __forceinline__
void g2_r(float2 (&a)[8], float4 R0, float4 R1) {
  const float2 A = a[RA], B = a[RB];
  a[RA] = cmul(make_float2(R0.x, R0.y), A) + cmul(make_float2(R0.z, R0.w), B);
  a[RB] = cmul(make_float2(R1.x, R1.y), A) + cmul(make_float2(R1.z, R1.w), B);
}
template <int RA, int RB> __device__ __forceinline__
void ry_pair(float2 (&a)[8], float c, float s) {
  const float2 A = a[RA], B = a[RB];
  a[RA] = f2b(c) * A - f2b(s) * B;
  a[RB] = f2b(s) * A + f2b(c) * B;
}
// CRX pair: A' = co*A + si*(A_im-swap of B):  re' = co*re + si*im_other,
// im' = co*im - si*re_other   (proven mapping, R6)
template <int RA, int RB> __device__ __forceinline__
void crx_pair(float2 (&a)[8], float co, float si) {
  const float2 A = a[RA], B = a[RB];
  a[RA] = f2b(co) * A + f2b(si) * make_float2(B.y, -B.x);
  a[RB] = f2b(co) * B + f2b(si) * make_float2(A.y, -A.x);
}

__global__ __launch_bounds__(256) void qcnn_fused(const float* __restrict__ x,
                                                  const float* __restrict__ w,
                                                  float* __restrict__ feats) {
  __shared__ float4 tauT[4][9];  // per-wave: qubit q -> (t0r, t0i, t1r, t1i)
  __shared__ float4 matT[30];    // [0..23] factor mats (12 x 2 rows); [24..29] M0_0, M0_1, M6_1
  __shared__ float2 sT[3];       // 0: (c,s) w40/2 CRX(6,0); 1: w41/2 fold; 2: (w35+w37)/2 RY6

  const int tid = threadIdx.x;
  const int wv = tid >> 6, lane = tid & 63;
  const unsigned p = blockIdx.x * 4u + wv;           // patch id (grid exact)
  const unsigned b = p / 676u;
  const unsigned rem = p - b * 676u;
  const unsigned i = rem / 26u, j = rem - i * 26u;

  // ---- per-wave patch-dependent table (all waves) ----
  if (lane < 9) {
    const int di = lane / 3, dj = lane - di * 3;
    const float xv = x[b * 784u + (i + di) * 28u + (j + dj)];
    const float ang = fmaf(xv, 3.14159265358979323846f, w[lane]) * 0.5f;
    float s, c; __sincosf(ang, &s, &c);
    float zs, zc; __sincosf(0.5f * w[9 + lane], &zs, &zc);
    tauT[wv][lane] = make_float4(c * zc, -c * zs, s * zc, s * zs);
  }

  // ---- weight-only tables: built ONCE by wave 0, shared block-wide ----
  if (wv == 0) {
    const bool isF = (lane >= 9 && lane < 21);   // 12 factor matrices
    const bool isM = (lane >= 24 && lane < 27);  // 3 post-expansion matrices
    if (isF || isM) {
      // compose M = RZ(z) * RY(c) * RX(bb) * RY(a)   (half-angle convention)
      float a = 0.f, bb = 0.f, c = 0.f, z = 0.f;
      int dst;
      if (isF) {
        const int k = lane - 9, ax = k >> 2, cb2 = k & 3;
        bb = ((cb2 & 1) ? w[18 + 2 * ax] : 0.f) + ((cb2 & 2) ? w[19 + 2 * ax] : 0.f);
        c = w[24 + ax]; z = w[27 + ax];
        dst = k;
      } else {
        const int m = lane - 24;
        if (m == 0)      { a = w[30] + w[34] + w[36]; z = w[38]; }
        else if (m == 1) { a = w[30]; bb = w[32]; c = w[34] + w[36]; z = w[38]; }
        else             { bb = w[33]; c = w[35] + w[37]; }
        dst = 12 + m;
      }
      float sa, ca, sb, cb, sc, cc, sz, cz;
      __sincosf(0.5f * a,  &sa, &ca);
      __sincosf(0.5f * bb, &sb, &cb);
      __sincosf(0.5f * c,  &sc, &cc);
      __sincosf(0.5f * z,  &sz, &cz);
      // A = RX(bb)*RY(a)
      const float A00r =  cb * ca, A00i = -sb * sa;
      const float A01r = -cb * sa, A01i = -sb * ca;
      const float A10r =  cb * sa, A10i = -sb * ca;
      const float A11r =  cb * ca, A11i =  sb * sa;
      // B = RY(c)*A
      const float B00r = cc * A00r - sc * A10r, B00i = cc * A00i - sc * A10i;
      const float B01r = cc * A01r - sc * A11r, B01i = cc * A01i - sc * A11i;
      const float B10r = sc * A00r + cc * A10r, B10i = sc * A00i + cc * A10i;
      const float B11r = sc * A01r + cc * A11r, B11i = sc * A01i + cc * A11i;
      // M = RZ(z)*B
      matT[dst * 2 + 0] = make_float4(cz * B00r + sz * B00i, cz * B00i - sz * B00r,
                                      cz * B01r + sz * B01i, cz * B01i - sz * B01r);
      matT[dst * 2 + 1] = make_float4(cz * B10r - sz * B10i, cz * B10i + sz * B10r,
                                      cz * B11r - sz * B11i, cz * B11i + sz * B11r);
    } else if (lane >= 27 && lane < 30) {
      const int k = lane - 27;
      const float th = (k == 0) ? w[40] : (k == 1) ? w[41] : (w[35] + w[37]);
      float s, c; __sincosf(0.5f * th, &s, &c);
      sT[k] = make_float2(c, s);
    }
  }
  __syncthreads();

  const int l0 = lane & 1, l1 = (lane >> 1) & 1, l2 = (lane >> 2) & 1;
  const int l3 = (lane >> 3) & 1, l4 = (lane >> 4) & 1, l5 = (lane >> 5) & 1;

  float4 tq[9];
#pragma unroll
  for (int q = 0; q < 9; ++q) tq[q] = tauT[wv][q];
  auto tau = [&](int bit, int q) -> float2 {
    const float4 t = tq[q];
    return bit ? make_float2(t.z, t.w) : make_float2(t.x, t.y);
  };

  // post-ring product-state factors (derivation verified R6/R7)
  const int a0 = l5, a1 = l0 ^ l5;
  float2 p00 = cmul(tau(a0, 0), tau(a1, 1));
  float2 p01 = cmul(tau(a0 ^ 1, 0), tau(a1 ^ 1, 1));
  float2 p10 = cmul(tau(l1, 3), tau(l2, 4));
  float2 p11 = cmul(tau(l1 ^ 1, 3), tau(l2 ^ 1, 4));
  float2 p20 = cmul(tau(l3, 6), tau(l4, 7));
  float2 p21 = cmul(tau(l3 ^ 1, 6), tau(l4 ^ 1, 7));
  const float2 T = cmul(cmul(tau(l0 ^ l1, 2), tau(l2 ^ l3, 5)), tau(l4 ^ l5, 8));
  p20 = cmul(p20, T);
  p21 = cmul(p21, T);

  // pool1 + conv2 as ONE pre-composed 2x2 per factor (LUT by control bits)
  {
    const int i0 = (lane & 3) << 1;
    const int i1 = (4 + ((lane >> 2) & 3)) << 1;
    const int i2 = (8 + ((lane >> 4) & 3)) << 1;
    g2_f(p00, p01, matT[i0], matT[i0 | 1]);
    g2_f(p10, p11, matT[i1], matT[i1 | 1]);
    g2_f(p20, p21, matT[i2], matT[i2 | 1]);
  }

  // expand with CX(0,3),CX(3,6),CX(6,0) FOLDED into the index map:
  //   v(b0,b1,b2) = p0(b0^b2) * p1(b0^b1^b2) * p2(b1^b2)
  float2 amp[8];
  {
    const float2 q00 = cmul(p00, p10);
    const float2 q01 = cmul(p00, p11);
    const float2 q10 = cmul(p01, p10);
    const float2 q11 = cmul(p01, p11);
    amp[0] = cmul(q00, p20);
    amp[1] = cmul(q11, p20);
    amp[2] = cmul(q01, p21);
    amp[3] = cmul(q10, p21);
    amp[4] = cmul(q11, p21);
    amp[5] = cmul(q00, p21);
    amp[6] = cmul(q10, p20);
    amp[7] = cmul(q01, p20);
  }

  // post-expansion gates via per-q3-half composed matrices.
  // b1=0 {0,1,4,5}: q0-pairs (0,1),(4,5) get M0_0; q6-pairs (0,4),(1,5) get RY6.
  // b1=1 {2,3,6,7}: q0-pairs (2,3),(6,7) get M0_1; q6-pairs (2,6),(3,7) get M6_1.
  // Then CX(0,6) (register rename 1<->5, 3<->7) and CRX(6,0,w40) on (4,5),(6,7).
  {
    const float4 A0 = matT[24], A1 = matT[25];
    const float4 B0 = matT[26], B1 = matT[27];
    const float4 C0 = matT[28], C1 = matT[29];
    const float2 s2 = sT[2];
    g2_r<0, 1>(amp, A0, A1); g2_r<4, 5>(amp, A0, A1);
    g2_r<2, 3>(amp, B0, B1); g2_r<6, 7>(amp, B0, B1);
    ry_pair<0, 4>(amp, s2.x, s2.y); ry_pair<1, 5>(amp, s2.x, s2.y);
    g2_r<2, 6>(amp, C0, C1); g2_r<3, 7>(amp, C0, C1);
    { float2 t = amp[1]; amp[1] = amp[5]; amp[5] = t; }   // CX(0,6)
    { float2 t = amp[3]; amp[3] = amp[7]; amp[7] = t; }
    const float2 sE = sT[0];
    crx_pair<4, 5>(amp, sE.x, sE.y);     // CRX(6,0) w40
    crx_pair<6, 7>(amp, sE.x, sE.y);
  }

  // <X>,<Y>,<Z> on qubit 0; packed-FMA partials, horizontal add at the end.
  float2 azr = f2b(0.f), azi = f2b(0.f), ape = f2b(0.f);
#pragma unroll
  for (int r0 = 0; r0 < 8; r0 += 2) {
    const float2 A = amp[r0], B = amp[r0 + 1];
    azr += A * B;                              // re0*re1 + im0*im1
    azi += A * make_float2(B.y, -B.x);         // re0*im1 - im0*re1
    ape += A * A;                              // |even|^2
  }
  float zr = azr.x + azr.y, zi = azi.x + azi.y, pe = ape.x + ape.y;
#pragma unroll
  for (int m = 1; m < 64; m <<= 1) { zr += shx(zr, m); zi += shx(zi, m); pe += shx(pe, m); }

  // RY(q0,w41) folded as a Bloch rotation about Y; all lanes compute,
  // lanes 0..2 issue ONE coalesced 12B store.
  {
    const float2 gF = sT[1];
    const float cT = gF.x * gF.x - gF.y * gF.y;
    const float sTT = 2.0f * gF.x * gF.y;
    const float ex = 2.0f * zr;
    const float ez = 2.0f * pe - 1.0f;
    const float fx = cT * ex + sTT * ez;
    const float fy = 2.0f * zi;
    const float fz = cT * ez - sTT * ex;
    if (lane < 3) {
      const float v = (lane == 0) ? fx : (lane == 1) ? fy : fz;
      feats[p * 3u + (unsigned)lane] = v;
    }
  }
}

// out[b,c] = fc_b[c] + dot(feats[b,:], fc_w[c,:]) over 2028 = 507 float4s.
__global__ __launch_bounds__(256) void fc_kernel(const float* __restrict__ feats,
                                                 const float* __restrict__ fc_w,
                                                 const float* __restrict__ fc_b,
                                                 float* __restrict__ out) {
  const int b = blockIdx.x / 10, c = blockIdx.x - b * 10;
  const float4* f  = reinterpret_cast<const float4*>(feats + b * 2028);
  const float4* wr = reinterpret_cast<const float4*>(fc_w + c * 2028);
  float acc = 0.0f;
  for (int k = threadIdx.x; k < 507; k += 256) {
    const float4 fv = f[k], wv4 = wr[k];
    acc += fv.x * wv4.x + fv.y * wv4.y + fv.z * wv4.z + fv.w * wv4.w;
  }
#pragma unroll
  for (int m = 1; m < 64; m <<= 1) acc += __shfl_xor(acc, m, 64);
  __shared__ float sbuf[4];
  const int lane = threadIdx.x & 63, wv = threadIdx.x >> 6;
  if (lane == 0) sbuf[wv] = acc;
  __syncthreads();
  if (threadIdx.x == 0) out[b * 10 + c] = sbuf[0] + sbuf[1] + sbuf[2] + sbuf[3] + fc_b[c];
}

extern "C" void kernel_launch(void* const* d_in, const int* in_sizes, int n_in,
                              void* d_out, int out_size, void* d_ws, size_t ws_size,
                              hipStream_t stream) {
  const float* x    = (const float*)d_in[0];   // (B,1,28,28)
  const float* w    = (const float*)d_in[1];   // (42,)
  const float* fc_w = (const float*)d_in[2];   // (10, 2028)
  const float* fc_b = (const float*)d_in[3];   // (10,)
  float* out = (float*)d_out;                  // (B, 10)

  const int B = in_sizes[0] / 784;             // 8
  const int npatch = B * 676;                  // 5408; divisible by 4

  float* feats = (float*)d_ws;                 // npatch*3 floats, fully written

  qcnn_fused<<<npatch / 4, 256, 0, stream>>>(x, w, feats);
  fc_kernel<<<B * 10, 256, 0, stream>>>(feats, fc_w, fc_b, out);
}